// Round 6
// baseline (372.542 us; speedup 1.0000x reference)
//
#include <hip/hip_runtime.h>
#include <hip/hip_bf16.h>

// Problem dims (fixed by the reference)
#define BB 8
#define NN 1024
#define MM 2048
#define DD 1024

typedef __attribute__((ext_vector_type(8))) __bf16 bfrag8;  // 8 bf16 = 4 VGPRs
typedef __attribute__((ext_vector_type(4))) float ffrag4;   // 4 fp32 acc

__device__ __forceinline__ unsigned short f2bf(float f) {
  union { float f; unsigned u; } x; x.f = f;
  unsigned r = x.u + 0x7FFFu + ((x.u >> 16) & 1u);
  return (unsigned short)(r >> 16);
}

#define LDA 40  // LDS row stride in ushorts: 32 k + 8 pad (16B-aligned rows)

// ---------------------------------------------------------------------------
// Kernel 0: zero the B*N fp32 row-sum accumulators (ws poisoned 0xAA).
// ---------------------------------------------------------------------------
__global__ void ta_zero(float* __restrict__ sums) {
  int t = blockIdx.x * 256 + threadIdx.x;
  if (t < BB * NN) sums[t] = 0.0f;
}

// ---------------------------------------------------------------------------
// Kernel 1: e[b,i,j] = exp( (Q.K)/32 - (i/N - j/M)^2/(2 s^2) ), 0 if j>=len.
// fp32 inputs, on-the-fly bf16 convert into LDS.  Writes UNNORMALIZED fp32 e
// into the attn output region (fp32 = reference output dtype); per-row sums
// via quad shuffle-reduce + one atomic per quad-row.
// 128x128 tile, BK=32, 256 threads = 4 waves (2x2), 4x4 16x16x32 MFMA / wave.
// C/D mapping (HW-verified R4==R5): col=lane&15, row=(lane>>4)*4+reg.
// ---------------------------------------------------------------------------
__global__ __launch_bounds__(256) void ta_gemm1e(
    const float* __restrict__ Q,   // (B,N,D)
    const float* __restrict__ K,   // (B,M,D)
    const float* __restrict__ sigma,
    const int* __restrict__ lens,
    float* __restrict__ attn,      // fp32 (B,N,M), unnormalized e out
    float* __restrict__ rowsum)    // (B*N,) fp32, pre-zeroed
{
  const int bj = blockIdx.x;       // M tile (16)
  const int bi = blockIdx.y;       // N tile (8)
  const int b  = blockIdx.z;
  const int t  = threadIdx.x;
  const int lane = t & 63;
  const int w  = t >> 6;
  const int wi = w >> 1, wj = w & 1;

  __shared__ unsigned short Als[128 * LDA];
  __shared__ unsigned short Bls[128 * LDA];

  const float* Qb = Q + (size_t)b * NN * DD + (size_t)(bi * 128) * DD;
  const float* Kb = K + (size_t)b * MM * DD + (size_t)(bj * 128) * DD;

  ffrag4 acc[4][4] = {};

  const int r    = lane & 15;
  const int koff = (lane >> 4) * 8;

  for (int k0 = 0; k0 < DD; k0 += 32) {
#pragma unroll
    for (int it = 0; it < 4; ++it) {
      int slot = t + 256 * it;
      int row  = slot >> 3;
      int c4   = slot & 7;
      float4 qa = *reinterpret_cast<const float4*>(Qb + (size_t)row * DD + k0 + c4 * 4);
      float4 ka = *reinterpret_cast<const float4*>(Kb + (size_t)row * DD + k0 + c4 * 4);
      ushort4 qh = { f2bf(qa.x), f2bf(qa.y), f2bf(qa.z), f2bf(qa.w) };
      ushort4 kh = { f2bf(ka.x), f2bf(ka.y), f2bf(ka.z), f2bf(ka.w) };
      *reinterpret_cast<ushort4*>(&Als[row * LDA + c4 * 4]) = qh;
      *reinterpret_cast<ushort4*>(&Bls[row * LDA + c4 * 4]) = kh;
    }
    __syncthreads();

    bfrag8 af[4], bf[4];
#pragma unroll
    for (int ti = 0; ti < 4; ++ti)
      af[ti] = *reinterpret_cast<const bfrag8*>(&Als[(wi * 64 + ti * 16 + r) * LDA + koff]);
#pragma unroll
    for (int tj = 0; tj < 4; ++tj)
      bf[tj] = *reinterpret_cast<const bfrag8*>(&Bls[(wj * 64 + tj * 16 + r) * LDA + koff]);

#pragma unroll
    for (int ti = 0; ti < 4; ++ti)
#pragma unroll
      for (int tj = 0; tj < 4; ++tj)
        acc[ti][tj] = __builtin_amdgcn_mfma_f32_16x16x32_bf16(af[ti], bf[tj], acc[ti][tj], 0, 0, 0);
    __syncthreads();
  }

  const float s = fabsf(sigma[0]) + 1e-8f;
  const float inv2s2 = 1.0f / (2.0f * s * s);
  const int len = lens[b];
  float* Prow = attn + (size_t)b * NN * MM;
  float* sums = rowsum + (size_t)b * NN;
  const int ibase = bi * 128 + wi * 64;
  const int jbase = bj * 128 + wj * 64;
  const int jc   = lane & 15;
  const int quad = lane >> 4;

#pragma unroll
  for (int ti = 0; ti < 4; ++ti) {
#pragma unroll
    for (int v = 0; v < 4; ++v) {
      int i = ibase + ti * 16 + quad * 4 + v;   // all 16 lanes of this quad: same i
      float psum = 0.0f;
#pragma unroll
      for (int tj = 0; tj < 4; ++tj) {
        int j = jbase + tj * 16 + jc;
        float e = 0.0f;
        if (j < len) {
          float dr = (float)i * (1.0f / (float)NN) - (float)j * (1.0f / (float)MM);
          float sc = acc[ti][tj][v] * 0.03125f - dr * dr * inv2s2;
          e = __expf(fminf(sc, 30.0f));
        }
        psum += e;
        Prow[(size_t)i * MM + j] = e;           // fp32 store, coalesced per quad
      }
      psum += __shfl_xor(psum, 1);
      psum += __shfl_xor(psum, 2);
      psum += __shfl_xor(psum, 4);
      psum += __shfl_xor(psum, 8);
      if (jc == 0) atomicAdd(&sums[i], psum);
    }
  }
}

// ---------------------------------------------------------------------------
// Kernel 2: in-place normalize fp32 attn by per-row sums.
// One thread handles one float4; 512 float4 per row (M=2048).
// ---------------------------------------------------------------------------
__global__ __launch_bounds__(256) void ta_norm(
    float* __restrict__ attn,
    const float* __restrict__ sums)
{
  int t = blockIdx.x * 256 + threadIdx.x;   // 0 .. B*N*M/4-1
  int row = t >> 9;                          // t*4 / 2048
  const float inv = 1.0f / fmaxf(sums[row], 1e-30f);
  float4* p = reinterpret_cast<float4*>(attn) + t;
  float4 x = *p;
  x.x *= inv; x.y *= inv; x.z *= inv; x.w *= inv;
  *p = x;
}

// ---------------------------------------------------------------------------
// Kernel 3: O[b,i,d] = sum_m P[b,i,m] * V[b,m,d].  P = normalized fp32 attn
// (converted to bf16 during staging), V = fp32 audio transposed+converted.
// fp32 output stores.
// ---------------------------------------------------------------------------
__global__ __launch_bounds__(256) void ta_gemm2(
    const float* __restrict__ P,   // fp32 (B,N,M), normalized
    const float* __restrict__ V,   // fp32 (B,M,D)
    float* __restrict__ O)         // fp32 (B,N,D)
{
  const int bd = blockIdx.x;       // D tile (8)
  const int bi = blockIdx.y;       // N tile (8)
  const int b  = blockIdx.z;
  const int t  = threadIdx.x;
  const int lane = t & 63;
  const int w  = t >> 6;
  const int wi = w >> 1, wj = w & 1;

  __shared__ unsigned short Pls[128 * LDA];  // row n, col k(=m)
  __shared__ unsigned short Vls[128 * LDA];  // row d, col k(=m)  (transposed)

  const float* Pb = P + (size_t)b * NN * MM + (size_t)(bi * 128) * MM;
  const float* Vb = V + (size_t)b * MM * DD + bd * 128;

  ffrag4 acc[4][4] = {};

  const int r    = lane & 15;
  const int koff = (lane >> 4) * 8;
  const int vd   = t & 127;        // d within tile
  const int vmb  = (t >> 7) * 16;  // m sub-block {0,16}

  for (int k0 = 0; k0 < MM; k0 += 32) {
    // Stage P: 128 rows x 32 fp32 -> bf16.  1024 float4 slots, 4/thread.
#pragma unroll
    for (int it = 0; it < 4; ++it) {
      int slot = t + 256 * it;
      int row  = slot >> 3;
      int c4   = slot & 7;
      float4 pa = *reinterpret_cast<const float4*>(Pb + (size_t)row * MM + k0 + c4 * 4);
      ushort4 ph = { f2bf(pa.x), f2bf(pa.y), f2bf(pa.z), f2bf(pa.w) };
      *reinterpret_cast<ushort4*>(&Pls[row * LDA + c4 * 4]) = ph;
    }
    // Stage V transposed: each thread owns one d-column, 16 consecutive m.
    union { unsigned short h[16]; uint4 q[2]; } hv;
#pragma unroll
    for (int i = 0; i < 16; ++i)
      hv.h[i] = f2bf(Vb[(size_t)(k0 + vmb + i) * DD + vd]);
    *reinterpret_cast<uint4*>(&Vls[vd * LDA + vmb])     = hv.q[0];
    *reinterpret_cast<uint4*>(&Vls[vd * LDA + vmb + 8]) = hv.q[1];
    __syncthreads();

    bfrag8 af[4], bf[4];
#pragma unroll
    for (int ti = 0; ti < 4; ++ti)
      af[ti] = *reinterpret_cast<const bfrag8*>(&Pls[(wi * 64 + ti * 16 + r) * LDA + koff]);
#pragma unroll
    for (int tj = 0; tj < 4; ++tj)
      bf[tj] = *reinterpret_cast<const bfrag8*>(&Vls[(wj * 64 + tj * 16 + r) * LDA + koff]);

#pragma unroll
    for (int ti = 0; ti < 4; ++ti)
#pragma unroll
      for (int tj = 0; tj < 4; ++tj)
        acc[ti][tj] = __builtin_amdgcn_mfma_f32_16x16x32_bf16(af[ti], bf[tj], acc[ti][tj], 0, 0, 0);
    __syncthreads();
  }

  float* Ob = O + (size_t)b * NN * DD;
  const int ibase = bi * 128 + wi * 64;
  const int dbase = bd * 128 + wj * 64;
#pragma unroll
  for (int ti = 0; ti < 4; ++ti) {
#pragma unroll
    for (int tj = 0; tj < 4; ++tj) {
      int d = dbase + tj * 16 + (lane & 15);
#pragma unroll
      for (int v = 0; v < 4; ++v) {
        int i = ibase + ti * 16 + (lane >> 4) * 4 + v;
        Ob[(size_t)i * DD + d] = acc[ti][tj][v];   // fp32 store
      }
    }
  }
}

// ---------------------------------------------------------------------------
extern "C" void kernel_launch(void* const* d_in, const int* in_sizes, int n_in,
                              void* d_out, int out_size, void* d_ws, size_t ws_size,
                              hipStream_t stream) {
  const float* text  = (const float*)d_in[0];  // (B,N,D) fp32
  const float* audio = (const float*)d_in[1];  // (B,M,D) fp32
  const float* sigma = (const float*)d_in[2];  // (1,) fp32
  const int*   lens  = (const int*)d_in[3];    // (B,) int32

  float* out = (float*)d_out;                  // fp32 outputs (reference dtype)
  float* enhanced = out;                       // B*N*D
  float* attn = out + (size_t)BB * NN * DD;    // B*N*M

  float* rowsum = (float*)d_ws;                // B*N fp32 = 32 KB scratch

  ta_zero<<<dim3((BB * NN + 255) / 256), 256, 0, stream>>>(rowsum);
  ta_gemm1e<<<dim3(MM / 128, NN / 128, BB), 256, 0, stream>>>(text, audio, sigma, lens, attn, rowsum);
  ta_norm<<<dim3(BB * NN * MM / 4 / 256), 256, 0, stream>>>(attn, rowsum);
  ta_gemm2<<<dim3(DD / 128, NN / 128, BB), 256, 0, stream>>>(attn, audio, enhanced);
}

// Round 7
// 301.374 us; speedup vs baseline: 1.2361x; 1.2361x over previous
//
#include <hip/hip_runtime.h>
#include <hip/hip_bf16.h>

#define BB 8
#define NN 1024
#define MM 2048
#define DD 1024

typedef __attribute__((ext_vector_type(8))) __bf16 bfrag8;  // 8 bf16 = 4 VGPRs
typedef __attribute__((ext_vector_type(4))) float ffrag4;   // 4 fp32 acc

__device__ __forceinline__ unsigned short f2bf(float f) {
  union { float f; unsigned u; } x; x.f = f;
  unsigned r = x.u + 0x7FFFu + ((x.u >> 16) & 1u);
  return (unsigned short)(r >> 16);
}

// async global->LDS, 16B per lane; LDS dst = wave-uniform base + lane*16
__device__ __forceinline__ void gload_lds16(const unsigned short* g, unsigned short* l) {
  __builtin_amdgcn_global_load_lds(
      (const __attribute__((address_space(1))) void*)g,
      (__attribute__((address_space(3))) void*)l, 16, 0, 0);
}

// ===========================================================================
// Tier A kernels (m97-style bf16 GEMMs + pre-convert passes)
// LDS layout per 128x32 bf16 tile: rows of 64 B, chunk-col XOR-swizzled:
// logical (row, chunk q) lives at physical chunk q ^ ((row^(row>>2))&3).
// -> staging writes (lane*16) and ds_read_b128 fragment reads conflict-free.
// ===========================================================================

// --- Q fp32 -> bf16 ---------------------------------------------------------
__global__ __launch_bounds__(256) void ta_cvtQ(const float* __restrict__ Q,
                                               unsigned short* __restrict__ Qbf) {
  int t = blockIdx.x * 256 + threadIdx.x;        // 1M threads, 8 elems each
  const float4* src = reinterpret_cast<const float4*>(Q) + t * 2;
  float4 a = src[0], b = src[1];
  ushort4 lo = { f2bf(a.x), f2bf(a.y), f2bf(a.z), f2bf(a.w) };
  ushort4 hi = { f2bf(b.x), f2bf(b.y), f2bf(b.z), f2bf(b.w) };
  ushort4* dst = reinterpret_cast<ushort4*>(Qbf) + t * 2;
  dst[0] = lo; dst[1] = hi;
}

// --- audio fp32 -> Kbf (row-major bf16) + VT (transposed bf16) -------------
#define TSTR 68  // LDS tile stride in ushorts (64 + 4 pad, 8B-aligned rows)
__global__ __launch_bounds__(256) void ta_trans(const float* __restrict__ V,
                                                unsigned short* __restrict__ Kbf,
                                                unsigned short* __restrict__ VT) {
  const int dt = blockIdx.x;     // D/64 = 16
  const int mt = blockIdx.y;     // M/64 = 32
  const int b  = blockIdx.z;
  const int t  = threadIdx.x;
  __shared__ unsigned short Tls[64 * TSTR];

  const float* Vb = V + (size_t)b * MM * DD + (size_t)(mt * 64) * DD + dt * 64;
#pragma unroll
  for (int it = 0; it < 4; ++it) {
    int slot = t + 256 * it;          // 0..1023
    int row  = slot >> 4;             // m within tile
    int c4   = slot & 15;             // float4 col
    float4 a = *reinterpret_cast<const float4*>(Vb + (size_t)row * DD + c4 * 4);
    ushort4 h = { f2bf(a.x), f2bf(a.y), f2bf(a.z), f2bf(a.w) };
    *reinterpret_cast<ushort4*>(&Tls[row * TSTR + c4 * 4]) = h;
  }
  __syncthreads();

  unsigned short* Kb = Kbf + (size_t)b * MM * DD + (size_t)(mt * 64) * DD + dt * 64;
  unsigned short* Vt = VT  + (size_t)b * DD * MM + (size_t)(dt * 64) * MM + mt * 64;
#pragma unroll
  for (int it = 0; it < 4; ++it) {
    int slot = t + 256 * it;
    int row  = slot >> 4;
    int c4   = slot & 15;
    // Kbf: straight copy out (coalesced)
    *reinterpret_cast<ushort4*>(Kb + (size_t)row * DD + c4 * 4) =
        *reinterpret_cast<const ushort4*>(&Tls[row * TSTR + c4 * 4]);
    // VT: transposed gather from LDS (row=d, col=m)
    ushort4 tv = { Tls[(c4 * 4 + 0) * TSTR + row],
                   Tls[(c4 * 4 + 1) * TSTR + row],
                   Tls[(c4 * 4 + 2) * TSTR + row],
                   Tls[(c4 * 4 + 3) * TSTR + row] };
    *reinterpret_cast<ushort4*>(Vt + (size_t)row * MM + c4 * 4) = tv;
  }
}

// --- zero rowsums -----------------------------------------------------------
__global__ void ta_zero(float* __restrict__ sums) {
  int t = blockIdx.x * 256 + threadIdx.x;
  if (t < BB * NN) sums[t] = 0.0f;
}

// --- GEMM1: e = exp(QK/32 + bias), bf16 out + rowsum ------------------------
__global__ __launch_bounds__(256) void ta_gemm1m(
    const unsigned short* __restrict__ Q,   // bf16 (B,N,D)
    const unsigned short* __restrict__ K,   // bf16 (B,M,D)
    const float* __restrict__ sigma,
    const int* __restrict__ lens,
    unsigned short* __restrict__ Ebf,       // bf16 (B,N,M) unnormalized e
    float* __restrict__ rowsum)
{
  const int bj = blockIdx.x, bi = blockIdx.y, b = blockIdx.z;
  const int t = threadIdx.x;
  const int lane = t & 63;
  const int w  = t >> 6;
  const int wi = w >> 1, wj = w & 1;

  __shared__ unsigned short As[4096];  // 128 rows x 32 bf16 (swizzled)
  __shared__ unsigned short Bs[4096];

  const unsigned short* Qb = Q + (size_t)b * NN * DD + (size_t)(bi * 128) * DD;
  const unsigned short* Kb = K + (size_t)b * MM * DD + (size_t)(bj * 128) * DD;

  ffrag4 acc[4][4] = {};

  const int r    = lane & 15;
  const int quad = lane >> 4;
  // staging constants: lane -> (row-in-chunk, physical chunk col) -> swizzled src col
  const int rc  = lane >> 2;
  const int sc8 = (((lane & 3) ^ ((rc ^ (rc >> 2)) & 3)) << 3);
  // fragment constants
  const int swz = (r ^ (r >> 2)) & 3;

  for (int k0 = 0; k0 < DD; k0 += 32) {
#pragma unroll
    for (int n = 0; n < 2; ++n) {
      int g = w * 2 + n;               // chunk 0..7 (16 rows each)
      int row = g * 16 + rc;
      gload_lds16(Qb + (size_t)row * DD + k0 + sc8, &As[g * 512]);
      gload_lds16(Kb + (size_t)row * DD + k0 + sc8, &Bs[g * 512]);
    }
    __syncthreads();

    bfrag8 af[4], bf[4];
#pragma unroll
    for (int ti = 0; ti < 4; ++ti)
      af[ti] = *reinterpret_cast<const bfrag8*>(&As[(wi * 64 + ti * 16 + r) * 32 + ((quad ^ swz) << 3)]);
#pragma unroll
    for (int tj = 0; tj < 4; ++tj)
      bf[tj] = *reinterpret_cast<const bfrag8*>(&Bs[(wj * 64 + tj * 16 + r) * 32 + ((quad ^ swz) << 3)]);

#pragma unroll
    for (int ti = 0; ti < 4; ++ti)
#pragma unroll
      for (int tj = 0; tj < 4; ++tj)
        acc[ti][tj] = __builtin_amdgcn_mfma_f32_16x16x32_bf16(af[ti], bf[tj], acc[ti][tj], 0, 0, 0);
    __syncthreads();
  }

  const float s = fabsf(sigma[0]) + 1e-8f;
  const float inv2s2 = 1.0f / (2.0f * s * s);
  const int len = lens[b];
  unsigned short* Erow = Ebf + (size_t)b * NN * MM;
  float* sums = rowsum + (size_t)b * NN;
  const int ibase = bi * 128 + wi * 64;
  const int jbase = bj * 128 + wj * 64;

#pragma unroll
  for (int ti = 0; ti < 4; ++ti) {
#pragma unroll
    for (int v = 0; v < 4; ++v) {
      int i = ibase + ti * 16 + quad * 4 + v;   // 16 lanes of quad: same i
      float psum = 0.0f;
#pragma unroll
      for (int tj = 0; tj < 4; ++tj) {
        int j = jbase + tj * 16 + r;
        float e = 0.0f;
        if (j < len) {
          float dr = (float)i * (1.0f / (float)NN) - (float)j * (1.0f / (float)MM);
          float sc = acc[ti][tj][v] * 0.03125f - dr * dr * inv2s2;
          e = __expf(fminf(sc, 30.0f));
        }
        psum += e;
        Erow[(size_t)i * MM + j] = f2bf(e);
      }
      psum += __shfl_xor(psum, 1);
      psum += __shfl_xor(psum, 2);
      psum += __shfl_xor(psum, 4);
      psum += __shfl_xor(psum, 8);
      if (r == 0) atomicAdd(&sums[i], psum);
    }
  }
}

// --- normalize: attn fp32 = Ebf / rowsum ------------------------------------
__global__ __launch_bounds__(256) void ta_normA(
    const unsigned short* __restrict__ Ebf,
    const float* __restrict__ sums,
    float* __restrict__ attn)
{
  int t = blockIdx.x * 256 + threadIdx.x;   // 0 .. B*N*M/8-1
  int row = t >> 8;                          // 8 elems/thread, M=2048
  const float inv = 1.0f / fmaxf(sums[row], 1e-30f);
  uint4 x = *(reinterpret_cast<const uint4*>(Ebf) + t);
  unsigned u[4] = { x.x, x.y, x.z, x.w };
  float o[8];
#pragma unroll
  for (int k = 0; k < 4; ++k) {
    union { unsigned u; float f; } lo, hi;
    lo.u = u[k] << 16; hi.u = u[k] & 0xFFFF0000u;
    o[2 * k]     = lo.f * inv;
    o[2 * k + 1] = hi.f * inv;
  }
  float4* dst = reinterpret_cast<float4*>(attn) + t * 2;
  float4 f0 = { o[0], o[1], o[2], o[3] };
  float4 f1 = { o[4], o[5], o[6], o[7] };
  dst[0] = f0; dst[1] = f1;
}

// --- GEMM2: O = (E @ V) / rowsum, fp32 out ----------------------------------
__global__ __launch_bounds__(256) void ta_gemm2m(
    const unsigned short* __restrict__ E,   // bf16 (B,N,M) unnormalized
    const unsigned short* __restrict__ VT,  // bf16 (B,D,M)
    const float* __restrict__ rowsum,
    float* __restrict__ O)                  // fp32 (B,N,D)
{
  const int bd = blockIdx.x, bi = blockIdx.y, b = blockIdx.z;
  const int t = threadIdx.x;
  const int lane = t & 63;
  const int w  = t >> 6;
  const int wi = w >> 1, wj = w & 1;

  __shared__ unsigned short As[4096];
  __shared__ unsigned short Bs[4096];

  const unsigned short* Eb = E  + (size_t)b * NN * MM + (size_t)(bi * 128) * MM;
  const unsigned short* Vb = VT + (size_t)b * DD * MM + (size_t)(bd * 128) * MM;

  ffrag4 acc[4][4] = {};

  const int r    = lane & 15;
  const int quad = lane >> 4;
  const int rc  = lane >> 2;
  const int sc8 = (((lane & 3) ^ ((rc ^ (rc >> 2)) & 3)) << 3);
  const int swz = (r ^ (r >> 2)) & 3;

  for (int k0 = 0; k0 < MM; k0 += 32) {
#pragma unroll
    for (int n = 0; n < 2; ++n) {
      int g = w * 2 + n;
      int row = g * 16 + rc;
      gload_lds16(Eb + (size_t)row * MM + k0 + sc8, &As[g * 512]);
      gload_lds16(Vb + (size_t)row * MM + k0 + sc8, &Bs[g * 512]);
    }
    __syncthreads();

    bfrag8 af[4], bf[4];
#pragma unroll
    for (int ti = 0; ti < 4; ++ti)
      af[ti] = *reinterpret_cast<const bfrag8*>(&As[(wi * 64 + ti * 16 + r) * 32 + ((quad ^ swz) << 3)]);
#pragma unroll
    for (int tj = 0; tj < 4; ++tj)
      bf[tj] = *reinterpret_cast<const bfrag8*>(&Bs[(wj * 64 + tj * 16 + r) * 32 + ((quad ^ swz) << 3)]);

#pragma unroll
    for (int ti = 0; ti < 4; ++ti)
#pragma unroll
      for (int tj = 0; tj < 4; ++tj)
        acc[ti][tj] = __builtin_amdgcn_mfma_f32_16x16x32_bf16(af[ti], bf[tj], acc[ti][tj], 0, 0, 0);
    __syncthreads();
  }

  float* Ob = O + (size_t)b * NN * DD;
  const float* rs = rowsum + (size_t)b * NN;
  const int ibase = bi * 128 + wi * 64;
  const int dbase = bd * 128 + wj * 64;
#pragma unroll
  for (int ti = 0; ti < 4; ++ti) {
#pragma unroll
    for (int v = 0; v < 4; ++v) {
      int i = ibase + ti * 16 + quad * 4 + v;
      float inv = 1.0f / fmaxf(rs[i], 1e-30f);
#pragma unroll
      for (int tj = 0; tj < 4; ++tj) {
        int d = dbase + tj * 16 + r;
        Ob[(size_t)i * DD + d] = acc[ti][tj][v] * inv;
      }
    }
  }
}

// ===========================================================================
// Tier B fallback (R6 kernels, pass at 372 us; needs only 32 KB ws)
// ===========================================================================
#define LDA 40
__global__ __launch_bounds__(256) void tb_gemm1e(
    const float* __restrict__ Q, const float* __restrict__ K,
    const float* __restrict__ sigma, const int* __restrict__ lens,
    float* __restrict__ attn, float* __restrict__ rowsum)
{
  const int bj = blockIdx.x, bi = blockIdx.y, b = blockIdx.z;
  const int t = threadIdx.x;
  const int lane = t & 63;
  const int w = t >> 6;
  const int wi = w >> 1, wj = w & 1;
  __shared__ unsigned short Als[128 * LDA];
  __shared__ unsigned short Bls[128 * LDA];
  const float* Qb = Q + (size_t)b * NN * DD + (size_t)(bi * 128) * DD;
  const float* Kb = K + (size_t)b * MM * DD + (size_t)(bj * 128) * DD;
  ffrag4 acc[4][4] = {};
  const int r = lane & 15;
  const int koff = (lane >> 4) * 8;
  for (int k0 = 0; k0 < DD; k0 += 32) {
#pragma unroll
    for (int it = 0; it < 4; ++it) {
      int slot = t + 256 * it;
      int row = slot >> 3, c4 = slot & 7;
      float4 qa = *reinterpret_cast<const float4*>(Qb + (size_t)row * DD + k0 + c4 * 4);
      float4 ka = *reinterpret_cast<const float4*>(Kb + (size_t)row * DD + k0 + c4 * 4);
      ushort4 qh = { f2bf(qa.x), f2bf(qa.y), f2bf(qa.z), f2bf(qa.w) };
      ushort4 kh = { f2bf(ka.x), f2bf(ka.y), f2bf(ka.z), f2bf(ka.w) };
      *reinterpret_cast<ushort4*>(&Als[row * LDA + c4 * 4]) = qh;
      *reinterpret_cast<ushort4*>(&Bls[row * LDA + c4 * 4]) = kh;
    }
    __syncthreads();
    bfrag8 af[4], bf[4];
#pragma unroll
    for (int ti = 0; ti < 4; ++ti)
      af[ti] = *reinterpret_cast<const bfrag8*>(&Als[(wi * 64 + ti * 16 + r) * LDA + koff]);
#pragma unroll
    for (int tj = 0; tj < 4; ++tj)
      bf[tj] = *reinterpret_cast<const bfrag8*>(&Bls[(wj * 64 + tj * 16 + r) * LDA + koff]);
#pragma unroll
    for (int ti = 0; ti < 4; ++ti)
#pragma unroll
      for (int tj = 0; tj < 4; ++tj)
        acc[ti][tj] = __builtin_amdgcn_mfma_f32_16x16x32_bf16(af[ti], bf[tj], acc[ti][tj], 0, 0, 0);
    __syncthreads();
  }
  const float s = fabsf(sigma[0]) + 1e-8f;
  const float inv2s2 = 1.0f / (2.0f * s * s);
  const int len = lens[b];
  float* Prow = attn + (size_t)b * NN * MM;
  float* sums = rowsum + (size_t)b * NN;
  const int ibase = bi * 128 + wi * 64;
  const int jbase = bj * 128 + wj * 64;
  const int quad = lane >> 4;
#pragma unroll
  for (int ti = 0; ti < 4; ++ti) {
#pragma unroll
    for (int v = 0; v < 4; ++v) {
      int i = ibase + ti * 16 + quad * 4 + v;
      float psum = 0.0f;
#pragma unroll
      for (int tj = 0; tj < 4; ++tj) {
        int j = jbase + tj * 16 + r;
        float e = 0.0f;
        if (j < len) {
          float dr = (float)i * (1.0f / (float)NN) - (float)j * (1.0f / (float)MM);
          float sc = acc[ti][tj][v] * 0.03125f - dr * dr * inv2s2;
          e = __expf(fminf(sc, 30.0f));
        }
        psum += e;
        Prow[(size_t)i * MM + j] = e;
      }
      psum += __shfl_xor(psum, 1);
      psum += __shfl_xor(psum, 2);
      psum += __shfl_xor(psum, 4);
      psum += __shfl_xor(psum, 8);
      if (r == 0) atomicAdd(&sums[i], psum);
    }
  }
}

__global__ __launch_bounds__(256) void tb_norm(float* __restrict__ attn,
                                               const float* __restrict__ sums) {
  int t = blockIdx.x * 256 + threadIdx.x;
  int row = t >> 9;
  const float inv = 1.0f / fmaxf(sums[row], 1e-30f);
  float4* p = reinterpret_cast<float4*>(attn) + t;
  float4 x = *p;
  x.x *= inv; x.y *= inv; x.z *= inv; x.w *= inv;
  *p = x;
}

__global__ __launch_bounds__(256) void tb_gemm2(
    const float* __restrict__ P, const float* __restrict__ V, float* __restrict__ O)
{
  const int bd = blockIdx.x, bi = blockIdx.y, b = blockIdx.z;
  const int t = threadIdx.x;
  const int lane = t & 63;
  const int w = t >> 6;
  const int wi = w >> 1, wj = w & 1;
  __shared__ unsigned short Pls[128 * LDA];
  __shared__ unsigned short Vls[128 * LDA];
  const float* Pb = P + (size_t)b * NN * MM + (size_t)(bi * 128) * MM;
  const float* Vb = V + (size_t)b * MM * DD + bd * 128;
  ffrag4 acc[4][4] = {};
  const int r = lane & 15;
  const int koff = (lane >> 4) * 8;
  const int vd = t & 127;
  const int vmb = (t >> 7) * 16;
  for (int k0 = 0; k0 < MM; k0 += 32) {
#pragma unroll
    for (int it = 0; it < 4; ++it) {
      int slot = t + 256 * it;
      int row = slot >> 3, c4 = slot & 7;
      float4 pa = *reinterpret_cast<const float4*>(Pb + (size_t)row * MM + k0 + c4 * 4);
      ushort4 ph = { f2bf(pa.x), f2bf(pa.y), f2bf(pa.z), f2bf(pa.w) };
      *reinterpret_cast<ushort4*>(&Pls[row * LDA + c4 * 4]) = ph;
    }
    union { unsigned short h[16]; uint4 q[2]; } hv;
#pragma unroll
    for (int i = 0; i < 16; ++i)
      hv.h[i] = f2bf(Vb[(size_t)(k0 + vmb + i) * DD + vd]);
    *reinterpret_cast<uint4*>(&Vls[vd * LDA + vmb]) = hv.q[0];
    *reinterpret_cast<uint4*>(&Vls[vd * LDA + vmb + 8]) = hv.q[1];
    __syncthreads();
    bfrag8 af[4], bf[4];
#pragma unroll
    for (int ti = 0; ti < 4; ++ti)
      af[ti] = *reinterpret_cast<const bfrag8*>(&Pls[(wi * 64 + ti * 16 + r) * LDA + koff]);
#pragma unroll
    for (int tj = 0; tj < 4; ++tj)
      bf[tj] = *reinterpret_cast<const bfrag8*>(&Vls[(wj * 64 + tj * 16 + r) * LDA + koff]);
#pragma unroll
    for (int ti = 0; ti < 4; ++ti)
#pragma unroll
      for (int tj = 0; tj < 4; ++tj)
        acc[ti][tj] = __builtin_amdgcn_mfma_f32_16x16x32_bf16(af[ti], bf[tj], acc[ti][tj], 0, 0, 0);
    __syncthreads();
  }
  float* Ob = O + (size_t)b * NN * DD;
  const int ibase = bi * 128 + wi * 64;
  const int dbase = bd * 128 + wj * 64;
#pragma unroll
  for (int ti = 0; ti < 4; ++ti) {
#pragma unroll
    for (int tj = 0; tj < 4; ++tj) {
      int d = dbase + tj * 16 + r;
#pragma unroll
      for (int v = 0; v < 4; ++v) {
        int i = ibase + ti * 16 + (lane >> 4) * 4 + v;
        Ob[(size_t)i * DD + d] = acc[ti][tj][v];
      }
    }
  }
}

// ---------------------------------------------------------------------------
extern "C" void kernel_launch(void* const* d_in, const int* in_sizes, int n_in,
                              void* d_out, int out_size, void* d_ws, size_t ws_size,
                              hipStream_t stream) {
  const float* text  = (const float*)d_in[0];
  const float* audio = (const float*)d_in[1];
  const float* sigma = (const float*)d_in[2];
  const int*   lens  = (const int*)d_in[3];

  float* out = (float*)d_out;
  float* enhanced = out;                       // B*N*D fp32
  float* attn = out + (size_t)BB * NN * DD;    // B*N*M fp32

  // Tier A ws layout (bytes)
  const size_t QBF  = (size_t)BB * NN * DD * 2;   // 16 MB
  const size_t KBF  = (size_t)BB * MM * DD * 2;   // 32 MB
  const size_t VTB  = (size_t)BB * DD * MM * 2;   // 32 MB
  const size_t EBF  = (size_t)BB * NN * MM * 2;   // 32 MB
  const size_t offQ = 65536;
  const size_t offK = offQ + QBF;
  const size_t offV = offK + KBF;
  const size_t offE = offV + VTB;
  const size_t need = offE + EBF;

  float* rowsum = (float*)d_ws;                // 32 KB @ 0

  if (ws_size >= need) {
    unsigned short* Qbf = (unsigned short*)((char*)d_ws + offQ);
    unsigned short* Kbf = (unsigned short*)((char*)d_ws + offK);
    unsigned short* VT  = (unsigned short*)((char*)d_ws + offV);
    unsigned short* Ebf = (unsigned short*)((char*)d_ws + offE);

    ta_zero<<<dim3((BB * NN + 255) / 256), 256, 0, stream>>>(rowsum);
    ta_cvtQ<<<dim3(BB * NN * DD / 8 / 256), 256, 0, stream>>>(text, Qbf);
    ta_trans<<<dim3(DD / 64, MM / 64, BB), 256, 0, stream>>>(audio, Kbf, VT);
    ta_gemm1m<<<dim3(MM / 128, NN / 128, BB), 256, 0, stream>>>(Qbf, Kbf, sigma, lens, Ebf, rowsum);
    ta_normA<<<dim3(BB * NN * MM / 8 / 256), 256, 0, stream>>>(Ebf, rowsum, attn);
    ta_gemm2m<<<dim3(DD / 128, NN / 128, BB), 256, 0, stream>>>(Ebf, VT, rowsum, enhanced);
  } else {
    ta_zero<<<dim3((BB * NN + 255) / 256), 256, 0, stream>>>(rowsum);
    tb_gemm1e<<<dim3(MM / 128, NN / 128, BB), 256, 0, stream>>>(text, audio, sigma, lens, attn, rowsum);
    tb_norm<<<dim3(BB * NN * MM / 4 / 256), 256, 0, stream>>>(attn, rowsum);
    tb_gemm2<<<dim3(DD / 128, NN / 128, BB), 256, 0, stream>>>(attn, audio, enhanced);
  }
}